// Round 3
// baseline (140.379 us; speedup 1.0000x reference)
//
#include <hip/hip_runtime.h>
#include <hip/hip_bf16.h>
#include <stdint.h>

#define NPTS 2048
#define DM 256
#define NH 4
#define DH 64
#define KK 1024

// ws layout (bytes):
//  [0,1MiB)   Qh bf16 [4][2048][64]
//  [1,2MiB)   Ql bf16
//  [2,3MiB)   Kh bf16
//  [3,4MiB)   Kl bf16
//  [4,6MiB)   V  f32  [4][2048][64]
#define QH_OFF_U16 0
#define QL_OFF_U16 (NH*NPTS*DH)          // 524288 ushorts
#define KH_OFF_U16 (2*NH*NPTS*DH)
#define KL_OFF_U16 (3*NH*NPTS*DH)
#define V_OFF_F32  (NH*NPTS*DH)          // in floats, after 4 MiB of bf16 (4*524288*2B = 4MiB = 1048576 floats... )
// careful: 4 bf16 arrays = 4*1MiB = 4MiB = 1048576 floats
#define V_OFF_FLOATS 1048576

typedef __attribute__((ext_vector_type(8))) short bf16x8;
typedef __attribute__((ext_vector_type(4))) float f32x4;

__device__ inline ushort bf16rn(float f) {
    uint32_t u = __float_as_uint(f);
    uint32_t r = (u + 0x7FFFu + ((u >> 16) & 1u)) >> 16;
    return (ushort)r;
}
__device__ inline float bf16tof(ushort h) {
    return __uint_as_float(((uint32_t)h) << 16);
}

// ---------------- Kernel 1: projections + rotary + bf16 hi/lo split ----------------
// grid (256, 3), block 256. z: 0=Q(rotary+scale->Qh/Ql), 1=K(rotary->Kh/Kl), 2=V(f32)
__global__ __launch_bounds__(256) void proj_rope_kernel(
    const float* __restrict__ xq, const float* __restrict__ xk, const float* __restrict__ xv,
    const float* __restrict__ emb,
    const float* __restrict__ Wq, const float* __restrict__ bq,
    const float* __restrict__ Wk, const float* __restrict__ bk,
    const float* __restrict__ Wv, const float* __restrict__ bv,
    float* __restrict__ ws)
{
    const int z = blockIdx.y;
    const int n0 = blockIdx.x * 8;
    const float* X = (z==0) ? xq : (z==1) ? xk : xv;
    const float* W = (z==0) ? Wq : (z==1) ? Wk : Wv;
    const float* B = (z==0) ? bq : (z==1) ? bk : bv;

    __shared__ float s_in[8][DM];
    {
        const float4* X4 = (const float4*)(X + (size_t)n0 * DM);
        float4* s4 = (float4*)&s_in[0][0];
        #pragma unroll
        for (int i = 0; i < 2; i++) {
            int f = threadIdx.x + 256*i;
            s4[f] = X4[f];
        }
    }
    __syncthreads();

    const int c = threadIdx.x;
    const int h = c >> 6, d = c & 63;
    const float bias = B[c];
    float acc[8];
    #pragma unroll
    for (int r = 0; r < 8; r++) acc[r] = bias;

    const float4* W4 = (const float4*)(W + (size_t)c * DM);
    #pragma unroll 4
    for (int k4 = 0; k4 < DM/4; k4++) {
        float4 w = W4[k4];
        #pragma unroll
        for (int r = 0; r < 8; r++) {
            float4 sv = *(const float4*)&s_in[r][k4*4];
            acc[r] = fmaf(sv.x, w.x, acc[r]);
            acc[r] = fmaf(sv.y, w.y, acc[r]);
            acc[r] = fmaf(sv.z, w.z, acc[r]);
            acc[r] = fmaf(sv.w, w.w, acc[r]);
        }
    }

    if (z < 2) {
        const int p = d >> 1;
        #pragma unroll
        for (int r = 0; r < 8; r++) {
            float th = emb[(size_t)(n0 + r)*(DM/2) + h*32 + p];
            float cs = cosf(th), sn = sinf(th);
            float partner = __shfl_xor(acc[r], 1);
            acc[r] = (d & 1) ? (acc[r]*cs + partner*sn) : (acc[r]*cs - partner*sn);
            if (z == 0) acc[r] *= 0.125f;   // 1/sqrt(64) folded into Q
        }
        // bf16 hi/lo split -> ws
        ushort* hi = (ushort*)ws + ((z==0) ? QH_OFF_U16 : KH_OFF_U16);
        ushort* lo = (ushort*)ws + ((z==0) ? QL_OFF_U16 : KL_OFF_U16);
        #pragma unroll
        for (int r = 0; r < 8; r++) {
            size_t idx = ((size_t)(h*NPTS + n0 + r))*DH + d;
            ushort hb = bf16rn(acc[r]);
            float res = acc[r] - bf16tof(hb);
            hi[idx] = hb;
            lo[idx] = bf16rn(res);
        }
    } else {
        float* V = ws + V_OFF_FLOATS;
        #pragma unroll
        for (int r = 0; r < 8; r++)
            V[((size_t)(h*NPTS + n0 + r))*DH + d] = acc[r];
    }
}

// ---------------- Kernel 2: scores via bf16x3 MFMA ----------------
// grid (32 colTiles, 32 rowTiles, 4 heads), block 256 (4 waves).
// Block tile: 64 rows x 64 cols. Wave w: rows wt*16.., all 64 cols (4 col-tiles).
// S = Qh*Kh + Qh*Kl + Ql*Kh  (lo*lo dropped, ~2^-16 rel err)
__global__ __launch_bounds__(256) void scores_mfma_kernel(const float* __restrict__ ws, float* __restrict__ sp)
{
    const ushort* qh = (const ushort*)ws + QH_OFF_U16;
    const ushort* ql = (const ushort*)ws + QL_OFF_U16;
    const ushort* kh = (const ushort*)ws + KH_OFF_U16;
    const ushort* kl = (const ushort*)ws + KL_OFF_U16;

    const int h = blockIdx.z;
    const int rbase = blockIdx.y * 64;
    const int cbase = blockIdx.x * 64;
    const int w = threadIdx.x >> 6, l = threadIdx.x & 63;
    const int lr = l & 15, g = l >> 4;

    // A fragments: row = rbase+w*16+lr, k-chunk for kstep s: k = 32s + 8g .. +7
    // (A and B use the SAME (laneGroup,reg)->k assignment, so any consistent
    //  k-permutation yields the correct dot product; only C layout must be exact.)
    const size_t arow = (size_t)(h*NPTS + rbase + w*16 + lr) * DH;
    bf16x8 a_h[2], a_l[2];
    #pragma unroll
    for (int s = 0; s < 2; s++) {
        a_h[s] = *(const bf16x8*)(qh + arow + 32*s + 8*g);
        a_l[s] = *(const bf16x8*)(ql + arow + 32*s + 8*g);
    }

    f32x4 acc[4];
    #pragma unroll
    for (int t = 0; t < 4; t++) acc[t] = (f32x4){0.f, 0.f, 0.f, 0.f};

    #pragma unroll
    for (int t = 0; t < 4; t++) {
        const size_t brow = (size_t)(h*NPTS + cbase + t*16 + lr) * DH;
        #pragma unroll
        for (int s = 0; s < 2; s++) {
            bf16x8 b_h = *(const bf16x8*)(kh + brow + 32*s + 8*g);
            bf16x8 b_l = *(const bf16x8*)(kl + brow + 32*s + 8*g);
            acc[t] = __builtin_amdgcn_mfma_f32_16x16x32_bf16(a_h[s], b_h, acc[t], 0, 0, 0);
            acc[t] = __builtin_amdgcn_mfma_f32_16x16x32_bf16(a_h[s], b_l, acc[t], 0, 0, 0);
            acc[t] = __builtin_amdgcn_mfma_f32_16x16x32_bf16(a_l[s], b_h, acc[t], 0, 0, 0);
        }
    }

    // C layout (m89-verified): col = lane&15, row = 4*(lane>>4) + reg
    #pragma unroll
    for (int t = 0; t < 4; t++) {
        const int col = cbase + t*16 + lr;
        #pragma unroll
        for (int r4 = 0; r4 < 4; r4++) {
            const int row = rbase + w*16 + g*4 + r4;
            sp[((size_t)(h*NPTS + row))*NPTS + col] = acc[t][r4];
        }
    }
}

// ---------------- Kernel 3: top-k + softmax + sparse write + hidden ----------------
__device__ inline uint32_t f2u(float f) {
    uint32_t x = __float_as_uint(f);
    return (x & 0x80000000u) ? ~x : (x | 0x80000000u);
}
__device__ inline float u2f(uint32_t u) {
    uint32_t x = (u & 0x80000000u) ? (u ^ 0x80000000u) : ~u;
    return __uint_as_float(x);
}

// grid (256, 4), block 512 (8 waves). Block = 8 query rows of one head, 1 row/wave.
__global__ __launch_bounds__(512, 4) void topk_attend_kernel(const float* __restrict__ ws, float* __restrict__ out)
{
    const int h  = blockIdx.y;
    const int n0 = blockIdx.x * 8;
    float* sp = out + (size_t)NPTS*DM;           // sparse region (raw scores on entry)
    __shared__ float s_s[8][NPTS];               // 64 KB: probs for PV
    __shared__ float s_hid[8][8][DH];            // 16 KB partials

    const int wave = threadIdx.x >> 6, lane = threadIdx.x & 63;
    const int row = wave;                        // one row per wave

    // phase 1: load this row's 2048 scores straight to registers (float4, coalesced).
    float* grow = sp + ((size_t)(h*NPTS + n0 + row))*NPTS;
    uint32_t u[32];
    #pragma unroll
    for (int j = 0; j < 8; j++) {
        float4 v = ((const float4*)grow)[lane + 64*j];
        u[4*j+0] = f2u(v.x); u[4*j+1] = f2u(v.y); u[4*j+2] = f2u(v.z); u[4*j+3] = f2u(v.w);
    }

    // row max
    uint32_t mu = 0u;
    #pragma unroll
    for (int j = 0; j < 32; j++) mu = (u[j] > mu) ? u[j] : mu;
    #pragma unroll
    for (int off = 32; off; off >>= 1) {
        uint32_t o = (uint32_t)__shfl_xor((int)mu, off);
        mu = (o > mu) ? o : mu;
    }
    const float mx = u2f(mu);

    // phase 2: exact 1024-th largest via binary search with ballot+popcount counting.
    uint32_t cur = 0u;
    for (int bit = 31; bit >= 0; bit--) {
        uint32_t cand = cur | (1u << bit);
        int c = 0;
        #pragma unroll
        for (int j = 0; j < 32; j++) c += (int)__popcll(__ballot(u[j] >= cand));
        if (c >= KK) { cur = cand; if (c == KK) break; }
    }

    // softmax over selected; exp results overwrite u[]
    float zsum = 0.f;
    #pragma unroll
    for (int j = 0; j < 32; j++) {
        bool sel = (u[j] >= cur);
        float f = u2f(u[j]);
        float ev = sel ? __expf(f - mx) : 0.f;
        u[j] = __float_as_uint(ev);
        zsum += ev;
    }
    #pragma unroll
    for (int off = 32; off; off >>= 1) zsum += __shfl_xor(zsum, off);
    const float rz = 1.f / zsum;

    // write probs: global (dense row, overwrites raw scores) + LDS for PV
    #pragma unroll
    for (int j = 0; j < 8; j++) {
        float4 p;
        p.x = __uint_as_float(u[4*j+0]) * rz;
        p.y = __uint_as_float(u[4*j+1]) * rz;
        p.z = __uint_as_float(u[4*j+2]) * rz;
        p.w = __uint_as_float(u[4*j+3]) * rz;
        ((float4*)grow)[lane + 64*j] = p;
        ((float4*)&s_s[row][0])[lane + 64*j] = p;
    }
    __syncthreads();

    // phase 3: hidden = P @ V. wave = m-chunk (256 m's), lane = d.
    const int d = lane;
    const float* V = ws + V_OFF_FLOATS + (size_t)h*NPTS*DH;
    float macc[8];
    #pragma unroll
    for (int r = 0; r < 8; r++) macc[r] = 0.f;
    const int mbase = wave * 256;
    for (int m = mbase; m < mbase + 256; m += 4) {
        float v0 = V[(size_t)(m+0)*DH + d];
        float v1 = V[(size_t)(m+1)*DH + d];
        float v2 = V[(size_t)(m+2)*DH + d];
        float v3 = V[(size_t)(m+3)*DH + d];
        #pragma unroll
        for (int r = 0; r < 8; r++) {
            float4 pv = *(const float4*)&s_s[r][m];   // wave-uniform addr -> broadcast
            macc[r] = fmaf(pv.x, v0, macc[r]);
            macc[r] = fmaf(pv.y, v1, macc[r]);
            macc[r] = fmaf(pv.z, v2, macc[r]);
            macc[r] = fmaf(pv.w, v3, macc[r]);
        }
    }
    #pragma unroll
    for (int r = 0; r < 8; r++) s_hid[wave][r][d] = macc[r];
    __syncthreads();

    {
        int idx = threadIdx.x;                        // 0..511 = 8 rows x 64 d
        int r = idx >> 6, dd = idx & 63;
        float s = 0.f;
        #pragma unroll
        for (int c2 = 0; c2 < 8; c2++) s += s_hid[c2][r][dd];
        out[(size_t)(n0 + r)*DM + h*DH + dd] = s;     // hidden[n][h*64+d]
    }
}

extern "C" void kernel_launch(void* const* d_in, const int* in_sizes, int n_in,
                              void* d_out, int out_size, void* d_ws, size_t ws_size,
                              hipStream_t stream)
{
    const float* xq  = (const float*)d_in[0];
    const float* xk  = (const float*)d_in[1];
    const float* xv  = (const float*)d_in[2];
    const float* emb = (const float*)d_in[3];
    const float* Wq  = (const float*)d_in[4];
    const float* bq  = (const float*)d_in[5];
    const float* Wk  = (const float*)d_in[6];
    const float* bk  = (const float*)d_in[7];
    const float* Wv  = (const float*)d_in[8];
    const float* bv  = (const float*)d_in[9];
    float* out = (float*)d_out;
    float* ws  = (float*)d_ws;   // needs 6 MiB

    proj_rope_kernel<<<dim3(NPTS/8, 3), 256, 0, stream>>>(xq, xk, xv, emb, Wq, bq, Wk, bk, Wv, bv, ws);
    scores_mfma_kernel<<<dim3(NPTS/64, NPTS/64, NH), 256, 0, stream>>>(ws, out + (size_t)NPTS*DM);
    topk_attend_kernel<<<dim3(NPTS/8, NH), 512, 0, stream>>>(ws, out);
}

// Round 4
// 115.862 us; speedup vs baseline: 1.2116x; 1.2116x over previous
//
#include <hip/hip_runtime.h>
#include <hip/hip_bf16.h>
#include <stdint.h>

#define NPTS 2048
#define DM 256
#define NH 4
#define DH 64
#define KK 1024

// ws layout (ushort units):
//  Qh bf16 [4][2048][64] @ 0
//  Ql bf16               @ 1*524288
//  Kh bf16               @ 2*524288
//  Kl bf16               @ 3*524288
//  Vt bf16 [4][64][2048] @ 4*524288   (transposed: channel-major)
#define QH_OFF 0
#define QL_OFF (NH*NPTS*DH)
#define KH_OFF (2*NH*NPTS*DH)
#define KL_OFF (3*NH*NPTS*DH)
#define VT_OFF (4*NH*NPTS*DH)

typedef __attribute__((ext_vector_type(8)))  short bf16x8;
typedef __attribute__((ext_vector_type(4)))  float f32x4;
typedef __attribute__((ext_vector_type(16))) float f32x16;

__device__ inline ushort bf16rn(float f) {
    uint32_t u = __float_as_uint(f);
    uint32_t r = (u + 0x7FFFu + ((u >> 16) & 1u)) >> 16;
    return (ushort)r;
}
__device__ inline float bf16tof(ushort h) {
    return __uint_as_float(((uint32_t)h) << 16);
}

// ---------------- Kernel 1: projections + rotary + bf16 hi/lo split + V^T ----------------
// grid (256, 3), block 256. z: 0=Q(rotary+scale->Qh/Ql), 1=K(rotary->Kh/Kl), 2=V(bf16 transposed)
__global__ __launch_bounds__(256) void proj_rope_kernel(
    const float* __restrict__ xq, const float* __restrict__ xk, const float* __restrict__ xv,
    const float* __restrict__ emb,
    const float* __restrict__ Wq, const float* __restrict__ bq,
    const float* __restrict__ Wk, const float* __restrict__ bk,
    const float* __restrict__ Wv, const float* __restrict__ bv,
    ushort* __restrict__ wsu)
{
    const int z = blockIdx.y;
    const int n0 = blockIdx.x * 8;
    const float* X = (z==0) ? xq : (z==1) ? xk : xv;
    const float* W = (z==0) ? Wq : (z==1) ? Wk : Wv;
    const float* B = (z==0) ? bq : (z==1) ? bk : bv;

    __shared__ float s_in[8][DM];
    {
        const float4* X4 = (const float4*)(X + (size_t)n0 * DM);
        float4* s4 = (float4*)&s_in[0][0];
        #pragma unroll
        for (int i = 0; i < 2; i++) {
            int f = threadIdx.x + 256*i;
            s4[f] = X4[f];
        }
    }
    __syncthreads();

    const int c = threadIdx.x;
    const int h = c >> 6, d = c & 63;
    const float bias = B[c];
    float acc[8];
    #pragma unroll
    for (int r = 0; r < 8; r++) acc[r] = bias;

    const float4* W4 = (const float4*)(W + (size_t)c * DM);
    #pragma unroll 4
    for (int k4 = 0; k4 < DM/4; k4++) {
        float4 w = W4[k4];
        #pragma unroll
        for (int r = 0; r < 8; r++) {
            float4 sv = *(const float4*)&s_in[r][k4*4];
            acc[r] = fmaf(sv.x, w.x, acc[r]);
            acc[r] = fmaf(sv.y, w.y, acc[r]);
            acc[r] = fmaf(sv.z, w.z, acc[r]);
            acc[r] = fmaf(sv.w, w.w, acc[r]);
        }
    }

    if (z < 2) {
        const int p = d >> 1;
        #pragma unroll
        for (int r = 0; r < 8; r++) {
            float th = emb[(size_t)(n0 + r)*(DM/2) + h*32 + p];
            float cs = cosf(th), sn = sinf(th);
            float partner = __shfl_xor(acc[r], 1);
            acc[r] = (d & 1) ? (acc[r]*cs + partner*sn) : (acc[r]*cs - partner*sn);
            if (z == 0) acc[r] *= 0.125f;   // 1/sqrt(64) folded into Q
        }
        // bf16 hi/lo split -> ws
        ushort* hi = wsu + ((z==0) ? QH_OFF : KH_OFF);
        ushort* lo = wsu + ((z==0) ? QL_OFF : KL_OFF);
        #pragma unroll
        for (int r = 0; r < 8; r++) {
            size_t idx = ((size_t)(h*NPTS + n0 + r))*DH + d;
            ushort hb = bf16rn(acc[r]);
            float res = acc[r] - bf16tof(hb);
            hi[idx] = hb;
            lo[idx] = bf16rn(res);
        }
    } else {
        // V: transpose via LDS, write bf16 Vt[channel c][n0..n0+7]
        __syncthreads();
        #pragma unroll
        for (int r = 0; r < 8; r++) s_in[r][c] = acc[r];
        __syncthreads();
        ushort tmp[8];
        #pragma unroll
        for (int r = 0; r < 8; r++) tmp[r] = bf16rn(s_in[r][c]);
        *(bf16x8*)(wsu + VT_OFF + (size_t)c*NPTS + n0) = *(bf16x8*)tmp;
    }
}

// ---------------- Kernel 2: scores via bf16x3 MFMA, 64x256 tiles ----------------
// grid (8 colTiles, 32 rowTiles, 4 heads), block 256 (4 waves: 2 row-bands x 2 col-bands).
// S = Qh*Kh + Qh*Kl + Ql*Kh  (lo*lo dropped)
__global__ __launch_bounds__(256) void scores_mfma_kernel(const ushort* __restrict__ wsu, float* __restrict__ sp)
{
    const ushort* qh = wsu + QH_OFF;
    const ushort* ql = wsu + QL_OFF;
    const ushort* kh = wsu + KH_OFF;
    const ushort* kl = wsu + KL_OFF;

    const int h = blockIdx.z;
    const int rbase = blockIdx.y * 64;
    const int cbase = blockIdx.x * 256;
    const int w = threadIdx.x >> 6, l = threadIdx.x & 63;
    const int r0 = rbase + (w & 1)*32;
    const int c0 = cbase + (w >> 1)*128;
    const int lr = l & 31, g = l >> 5;

    // A fragments (Q): row = r0+lr, k = 16s + 8g + i  (same k-map for A and B)
    const size_t abase = ((size_t)(h*NPTS + r0 + lr))*DH + 8*g;
    bf16x8 a_h[4], a_l[4];
    #pragma unroll
    for (int s = 0; s < 4; s++) {
        a_h[s] = *(const bf16x8*)(qh + abase + 16*s);
        a_l[s] = *(const bf16x8*)(ql + abase + 16*s);
    }

    f32x16 acc[4];
    #pragma unroll
    for (int t = 0; t < 4; t++)
        #pragma unroll
        for (int e = 0; e < 16; e++) acc[t][e] = 0.f;

    #pragma unroll
    for (int t = 0; t < 4; t++) {
        const size_t bbase = ((size_t)(h*NPTS + c0 + t*32 + lr))*DH + 8*g;
        #pragma unroll
        for (int s = 0; s < 4; s++) {
            bf16x8 bh = *(const bf16x8*)(kh + bbase + 16*s);
            bf16x8 bl = *(const bf16x8*)(kl + bbase + 16*s);
            acc[t] = __builtin_amdgcn_mfma_f32_32x32x16_bf16(a_h[s], bh, acc[t], 0, 0, 0);
            acc[t] = __builtin_amdgcn_mfma_f32_32x32x16_bf16(a_h[s], bl, acc[t], 0, 0, 0);
            acc[t] = __builtin_amdgcn_mfma_f32_32x32x16_bf16(a_l[s], bh, acc[t], 0, 0, 0);
        }
    }

    // C layout (m74/m101): col = lane&31, row = (reg&3) + 8*(reg>>2) + 4*(lane>>5)
    #pragma unroll
    for (int t = 0; t < 4; t++) {
        const int col = c0 + t*32 + lr;
        #pragma unroll
        for (int reg = 0; reg < 16; reg++) {
            const int row = r0 + 4*g + (reg & 3) + 8*(reg >> 2);
            sp[((size_t)(h*NPTS + row))*NPTS + col] = acc[t][reg];
        }
    }
}

// ---------------- Kernel 3: top-k + softmax + sparse write + MFMA PV ----------------
__device__ inline uint32_t f2u(float f) {
    uint32_t x = __float_as_uint(f);
    return (x & 0x80000000u) ? ~x : (x | 0x80000000u);
}
__device__ inline float u2f(uint32_t u) {
    uint32_t x = (u & 0x80000000u) ? (u ^ 0x80000000u) : ~u;
    return __uint_as_float(x);
}

// grid (256, 4), block 512 (8 waves). Block = 8 query rows of one head, 1 row/wave.
__global__ __launch_bounds__(512, 6) void topk_attend_kernel(const ushort* __restrict__ wsu, float* __restrict__ out)
{
    const int h  = blockIdx.y;
    const int n0 = blockIdx.x * 8;
    float* sp = out + (size_t)NPTS*DM;           // sparse region (raw scores on entry)
    __shared__ ushort s_p[8][NPTS];              // 32 KB bf16 probs (16B-chunk XOR swizzle per row)
    __shared__ float s_hid[8][8][DH];            // 16 KB PV partials

    const int wave = threadIdx.x >> 6, lane = threadIdx.x & 63;
    const int row = wave;

    // phase 1: row scores -> registers (coalesced float4). slot (j,i) holds m=4*(lane+64j)+i.
    float* grow = sp + ((size_t)(h*NPTS + n0 + row))*NPTS;
    uint32_t u[32];
    #pragma unroll
    for (int j = 0; j < 8; j++) {
        float4 v = ((const float4*)grow)[lane + 64*j];
        u[4*j+0] = f2u(v.x); u[4*j+1] = f2u(v.y); u[4*j+2] = f2u(v.z); u[4*j+3] = f2u(v.w);
    }

    // row max
    uint32_t mu = 0u;
    #pragma unroll
    for (int j = 0; j < 32; j++) mu = (u[j] > mu) ? u[j] : mu;
    #pragma unroll
    for (int off = 32; off; off >>= 1) {
        uint32_t o = (uint32_t)__shfl_xor((int)mu, off);
        mu = (o > mu) ? o : mu;
    }
    const float mx = u2f(mu);

    // phase 2: exact 1024-th largest, ballot+popcount binary search with early exit
    uint32_t cur = 0u;
    for (int bit = 31; bit >= 0; bit--) {
        uint32_t cand = cur | (1u << bit);
        int c = 0;
        #pragma unroll
        for (int j = 0; j < 32; j++) c += (int)__popcll(__ballot(u[j] >= cand));
        if (c >= KK) { cur = cand; if (c == KK) break; }
    }

    // softmax over selected; exp overwrites u[]
    float zsum = 0.f;
    #pragma unroll
    for (int j = 0; j < 32; j++) {
        bool sel = (u[j] >= cur);
        float f = u2f(u[j]);
        float ev = sel ? __expf(f - mx) : 0.f;
        u[j] = __float_as_uint(ev);
        zsum += ev;
    }
    #pragma unroll
    for (int off = 32; off; off >>= 1) zsum += __shfl_xor(zsum, off);
    const float rz = 1.f / zsum;

    // write probs: global f32 (output) + LDS bf16 (swizzled) for MFMA PV
    char* srow = (char*)&s_p[row][0];
    const uint32_t swz = (uint32_t)((row & 7) << 4);
    #pragma unroll
    for (int j = 0; j < 8; j++) {
        float4 p;
        p.x = __uint_as_float(u[4*j+0]) * rz;
        p.y = __uint_as_float(u[4*j+1]) * rz;
        p.z = __uint_as_float(u[4*j+2]) * rz;
        p.w = __uint_as_float(u[4*j+3]) * rz;
        ((float4*)grow)[lane + 64*j] = p;
        uint32_t pk0 = ((uint32_t)bf16rn(p.y) << 16) | bf16rn(p.x);
        uint32_t pk1 = ((uint32_t)bf16rn(p.w) << 16) | bf16rn(p.z);
        uint32_t boff = (8u*lane + 512u*j) ^ swz;    // byte 2*m, XOR moves whole 16B chunk
        *(uint2*)(srow + boff) = make_uint2(pk0, pk1);
    }
    __syncthreads();

    // phase 3: PV via MFMA 16x16x32 bf16. C^T = Vt(64d x 2048m) * P^T(2048m x 8r).
    // wave handles m-chunk [256*wave, 256*wave+256): 8 ksteps x 4 d-tiles.
    const ushort* Vt = wsu + VT_OFF + (size_t)h*DH*NPTS;
    const int m0 = wave * 256;
    const int cg = lane >> 4;          // k-group 0..3 (k = 8*cg + i within 32-step)
    const int cl = lane & 15;          // A row (d-in-tile) selector / B col
    const int prow = cl & 7;           // P row (cols 8..15 duplicate, discarded)
    f32x4 pacc[4];
    #pragma unroll
    for (int dt = 0; dt < 4; dt++) pacc[dt] = (f32x4){0.f,0.f,0.f,0.f};

    const char* pbase = (const char*)&s_p[prow][0];
    const uint32_t pswz = (uint32_t)((prow & 7) << 4);
    for (int s = 0; s < 8; s++) {
        const int mk = m0 + 32*s + 8*cg;
        uint32_t boff = ((uint32_t)(2*mk)) ^ pswz;
        bf16x8 bfrag = *(const bf16x8*)(pbase + boff);
        #pragma unroll
        for (int dt = 0; dt < 4; dt++) {
            bf16x8 afrag = *(const bf16x8*)(Vt + ((size_t)(16*dt + cl))*NPTS + mk);
            pacc[dt] = __builtin_amdgcn_mfma_f32_16x16x32_bf16(afrag, bfrag, pacc[dt], 0, 0, 0);
        }
    }
    // C layout: col = lane&15 (= r), row-in-tile = 4*(lane>>4) + reg (= d offset)
    if (cl < 8) {
        #pragma unroll
        for (int dt = 0; dt < 4; dt++)
            #pragma unroll
            for (int reg = 0; reg < 4; reg++)
                s_hid[wave][cl][16*dt + 4*cg + reg] = pacc[dt][reg];
    }
    __syncthreads();

    {
        int idx = threadIdx.x;                        // 0..511 = 8 rows x 64 d
        int r = idx >> 6, dd = idx & 63;
        float s = 0.f;
        #pragma unroll
        for (int c2 = 0; c2 < 8; c2++) s += s_hid[c2][r][dd];
        out[(size_t)(n0 + r)*DM + h*DH + dd] = s;     // hidden[n][h*64+d]
    }
}

extern "C" void kernel_launch(void* const* d_in, const int* in_sizes, int n_in,
                              void* d_out, int out_size, void* d_ws, size_t ws_size,
                              hipStream_t stream)
{
    const float* xq  = (const float*)d_in[0];
    const float* xk  = (const float*)d_in[1];
    const float* xv  = (const float*)d_in[2];
    const float* emb = (const float*)d_in[3];
    const float* Wq  = (const float*)d_in[4];
    const float* bq  = (const float*)d_in[5];
    const float* Wk  = (const float*)d_in[6];
    const float* bk  = (const float*)d_in[7];
    const float* Wv  = (const float*)d_in[8];
    const float* bv  = (const float*)d_in[9];
    float* out  = (float*)d_out;
    ushort* wsu = (ushort*)d_ws;   // needs 5 MiB

    proj_rope_kernel<<<dim3(NPTS/8, 3), 256, 0, stream>>>(xq, xk, xv, emb, Wq, bq, Wk, bk, Wv, bv, wsu);
    scores_mfma_kernel<<<dim3(NPTS/256, NPTS/64, NH), 256, 0, stream>>>(wsu, out + (size_t)NPTS*DM);
    topk_attend_kernel<<<dim3(NPTS/8, NH), 512, 0, stream>>>(wsu, out);
}